// Round 6
// baseline (490.858 us; speedup 1.0000x reference)
//
#include <hip/hip_runtime.h>
#include <hip/hip_bf16.h>

// Head: B=8, T=4096, E=1024, H=64. out = softmax_causal(QK^T/8) V, fp32 out.
// R6: attn decomposed over keys (fixed-ref softmax => unnormalized o,l are
// plain sums): 1280 blocks of (b, 64q, 1024-key chunk), <=16 iters each,
// LPT-ordered, partial (o,l) fp32 in ws slots + combine kernel. proj:
// barrier-free streaming (B direct from L2-hot wt3, A reg-dbuf), 1024 blocks.

#define BB 8
#define TT 4096
#define EE 1024
#define HH 64
#define BT (BB * TT)

typedef __attribute__((ext_vector_type(8))) short short8;
typedef __attribute__((ext_vector_type(4))) float floatx4;
typedef short8 __attribute__((may_alias)) short8_a;
typedef uint2 __attribute__((may_alias)) uint2_a;
typedef uint4 __attribute__((may_alias)) uint4_a;
typedef float4 __attribute__((may_alias)) float4_a;

#define GLDS(gp, lp)                                                     \
  __builtin_amdgcn_global_load_lds(                                      \
      (const __attribute__((address_space(1))) unsigned int*)(gp),       \
      (__attribute__((address_space(3))) unsigned int*)(lp), 16, 0, 0)

__device__ __forceinline__ unsigned short f2bf(float f) {
  union { float f; unsigned int u; } v; v.f = f;
  unsigned int r = v.u + 0x7fffu + ((v.u >> 16) & 1u);  // RNE
  return (unsigned short)(r >> 16);
}
__device__ __forceinline__ unsigned int pk2(float a, float b) {
  return (unsigned int)f2bf(a) | ((unsigned int)f2bf(b) << 16);
}
__device__ __forceinline__ floatx4 fzero() {
  floatx4 z = {0.f, 0.f, 0.f, 0.f};
  return z;
}
__device__ __forceinline__ floatx4 mfma_bf16(short8 a, short8 b, floatx4 c) {
  return __builtin_amdgcn_mfma_f32_16x16x32_bf16(a, b, c, 0, 0, 0);
}
__device__ __forceinline__ short8 pack8(float4 a, float4 b) {
  union { unsigned int u[4]; short8 s; } r;
  r.u[0] = pk2(a.x, a.y);
  r.u[1] = pk2(a.z, a.w);
  r.u[2] = pk2(b.x, b.y);
  r.u[3] = pk2(b.z, b.w);
  return r.s;
}

// ---------------------------------------------------------------------------
// Kernel 1: W[e][h] fp32 -> wt3[m][h][e] bf16 (m=0:K,1:Q,2:V). 48 blocks.
// ---------------------------------------------------------------------------
__global__ __launch_bounds__(256) void wt_kernel(
    const float* __restrict__ Wk, const float* __restrict__ Wq,
    const float* __restrict__ Wv, unsigned short* __restrict__ wt3) {
  __shared__ float tile[64][65];
  const int m = blockIdx.y;
  const int eb = blockIdx.x;  // e-block of 64
  const float* W = (m == 0) ? Wk : ((m == 1) ? Wq : Wv);
  const int t = threadIdx.x;
  {
    const int r = t >> 2;            // e-local
    const int c0 = (t & 3) * 16;     // h
    const float* src = W + (size_t)(eb * 64 + r) * 64 + c0;
#pragma unroll
    for (int i = 0; i < 16; ++i) tile[r][c0 + i] = src[i];
  }
  __syncthreads();
  {
    const int h = t >> 2;
    const int e0 = (t & 3) * 16;
    unsigned int w[8];
#pragma unroll
    for (int i = 0; i < 8; ++i)
      w[i] = pk2(tile[e0 + 2 * i][h], tile[e0 + 2 * i + 1][h]);
    unsigned short* dst = wt3 + (size_t)(m * 64 + h) * EE + eb * 64 + e0;
    ((uint4_a*)dst)[0] = make_uint4(w[0], w[1], w[2], w[3]);
    ((uint4_a*)(dst + 8))[0] = make_uint4(w[4], w[5], w[6], w[7]);
  }
}

// ---------------------------------------------------------------------------
// Kernel 2: projections, barrier-free streaming. 1024 blocks x 256 thr;
// block = 32 rows, wave wv owns col-tiles wv*3..wv*3+2 (x2 row-frags).
// A direct-to-reg (parity dbuf, prefetch c+1); B direct from wt3 (24 KB/chunk,
// L1/L2-hot). No LDS, no barriers. Q pre-scaled by 0.125.
// ---------------------------------------------------------------------------
__global__ __launch_bounds__(256) void proj_kernel(
    const float* __restrict__ x, const unsigned short* __restrict__ wt3,
    unsigned short* __restrict__ kws, unsigned short* __restrict__ qws,
    unsigned short* __restrict__ vtws) {
  const int t = threadIdx.x;
  const int wv = t >> 6, lane = t & 63;
  const int l16 = lane & 15, quad = lane >> 4;
  const size_t row0 = (size_t)blockIdx.x * 32;

  floatx4 acc[3][2];
#pragma unroll
  for (int j = 0; j < 3; ++j)
#pragma unroll
    for (int m2 = 0; m2 < 2; ++m2) acc[j][m2] = fzero();

  // A: lane (l16,quad) -> rows row0+l16 (+16), k = c*64 + f*32 + quad*8
  const float* xb = x + (row0 + l16) * EE + quad * 8;

  float4 buf[2][2][2][2];  // [parity][m2][f][g]
#pragma unroll
  for (int m2 = 0; m2 < 2; ++m2)
#pragma unroll
    for (int f = 0; f < 2; ++f)
#pragma unroll
      for (int g = 0; g < 2; ++g)
        buf[0][m2][f][g] =
            *(const float4_a*)(xb + (size_t)m2 * 16 * EE + f * 32 + g * 4);

  for (int c = 0; c < 16; ++c) {
    const int cur = c & 1;
    if (c < 15) {  // prefetch next chunk
#pragma unroll
      for (int m2 = 0; m2 < 2; ++m2)
#pragma unroll
        for (int f = 0; f < 2; ++f)
#pragma unroll
          for (int g = 0; g < 2; ++g)
            buf[cur ^ 1][m2][f][g] = *(const float4_a*)(
                xb + (size_t)m2 * 16 * EE + (c + 1) * 64 + f * 32 + g * 4);
    }
    short8 af[2][2];
#pragma unroll
    for (int m2 = 0; m2 < 2; ++m2)
#pragma unroll
      for (int f = 0; f < 2; ++f)
        af[m2][f] = pack8(buf[cur][m2][f][0], buf[cur][m2][f][1]);
#pragma unroll
    for (int j = 0; j < 3; ++j) {
      const int jg = wv * 3 + j;
      const unsigned short* wp =
          wt3 + (size_t)((jg >> 2) * 64 + (jg & 3) * 16 + l16) * EE + c * 64 +
          quad * 8;
      short8 b0 = *(const short8_a*)(wp);
      short8 b1 = *(const short8_a*)(wp + 32);
#pragma unroll
      for (int m2 = 0; m2 < 2; ++m2) {
        acc[j][m2] = mfma_bf16(af[m2][0], b0, acc[j][m2]);
        acc[j][m2] = mfma_bf16(af[m2][1], b1, acc[j][m2]);
      }
    }
  }

  const int b = (int)(row0 >> 12);
  const int tt0 = (int)(row0 & (TT - 1));
#pragma unroll
  for (int j = 0; j < 3; ++j) {
    const int jg = wv * 3 + j;
    const int m = jg >> 2;
    const int h0 = (jg & 3) * 16;
#pragma unroll
    for (int m2 = 0; m2 < 2; ++m2) {
      floatx4 a = acc[j][m2];
      const int rbase = m2 * 16 + quad * 4;
      if (m == 0) {
#pragma unroll
        for (int r = 0; r < 4; ++r)
          kws[(row0 + rbase + r) * HH + h0 + l16] = f2bf(a[r]);
      } else if (m == 1) {
#pragma unroll
        for (int r = 0; r < 4; ++r)
          qws[(row0 + rbase + r) * HH + h0 + l16] = f2bf(a[r] * 0.125f);
      } else {  // v transposed [B,64,T]
        uint2 p;
        p.x = pk2(a[0], a[1]);
        p.y = pk2(a[2], a[3]);
        ((uint2_a*)&vtws[(size_t)(b * 64 + h0 + l16) * TT + tt0 + rbase])[0] = p;
      }
    }
  }
}

// ---------------------------------------------------------------------------
// Kernel 3: attention pass 1. Item = (b, 64q tile jq, 1024-key chunk s);
// 1280 blocks, LPT order (16-iter full chunks first). Fixed-ref softmax:
// partial o = sum exp(s)*v (unnormalized), partial l = sum exp(s) -> ws
// slots, disjoint writes, no atomics. KV single-buffer frag-contig LDS.
// b = blockIdx&7 -> XCD-local K/V.
// ---------------------------------------------------------------------------
__global__ __launch_bounds__(256) void attn_kernel(
    const unsigned short* __restrict__ kws, const unsigned short* __restrict__ qws,
    const unsigned short* __restrict__ vtws, float* __restrict__ o_part,
    float* __restrict__ l_part) {
  __shared__ unsigned short KV[16][512];  // 16 KB, frags 0..7=K, 8..15=V
  __shared__ unsigned short pb[4][16][72];
  const int t = threadIdx.x;
  const int wv = t >> 6, lane = t & 63;
  const int l16 = lane & 15, quad = lane >> 4;
  const int g = (int)blockIdx.x;
  const int b = g & 7;
  const int i = g >> 3;  // 0..159, cost-descending item within batch
  int s, jq;
  if (i < 49)       { s = 0; jq = 15 + i; }
  else if (i < 82)  { s = 1; jq = 31 + (i - 49); }
  else if (i < 99)  { s = 2; jq = 47 + (i - 82); }
  else if (i == 99) { s = 3; jq = 63; }
  else if (i < 115) { s = 0; jq = 114 - i; }
  else if (i < 130) { s = 1; jq = 16 + (129 - i); }
  else if (i < 145) { s = 2; jq = 32 + (144 - i); }
  else              { s = 3; jq = 48 + (159 - i); }
  const int k0 = s * 16;                       // first 64-key tile
  const int nit = min(16, jq + 1 - k0);        // iterations (>=1)
  const int q0 = jq * 64;
  const int qrow = q0 + wv * 16 + l16;

  const unsigned short* qp = qws + ((size_t)b * TT + qrow) * HH + quad * 8;
  short8 qa0 = *(const short8_a*)(qp);
  short8 qa1 = *(const short8_a*)(qp + 32);

  floatx4 o[4];
#pragma unroll
  for (int nt = 0; nt < 4; ++nt) o[nt] = fzero();
  float lsum = 0.f;

#define STAGE_KV(ks)                                                          \
  {                                                                           \
    _Pragma("unroll") for (int ii = 0; ii < 4; ++ii) {                        \
      const int idx = wv * 4 + ii;                                            \
      const unsigned short* gp;                                               \
      if (idx < 8) {                                                          \
        const int nt = idx >> 1, f = idx & 1;                                 \
        gp = kws + ((size_t)b * TT + (ks) + nt * 16 + l16) * HH + f * 32 +    \
             quad * 8;                                                        \
      } else {                                                                \
        const int nt = (idx - 8) >> 1, f = idx & 1;                           \
        gp = vtws + ((size_t)(b * 64 + nt * 16 + l16)) * TT + (ks) + f * 32 + \
             quad * 8;                                                        \
      }                                                                       \
      GLDS(gp, &KV[idx][0]);                                                  \
    }                                                                         \
  }

  STAGE_KV(k0 * 64);
  __syncthreads();

  for (int it = 0; it < nit; ++it) {
    const int kt = k0 + it;
    const int ks = kt * 64;

    floatx4 sv[4];
#pragma unroll
    for (int nt = 0; nt < 4; ++nt) {
      short8 kf0 = *(const short8_a*)&KV[nt * 2][lane * 8];
      short8 kf1 = *(const short8_a*)&KV[nt * 2 + 1][lane * 8];
      floatx4 z = fzero();
      z = mfma_bf16(kf0, qa0, z);
      z = mfma_bf16(kf1, qa1, z);
      sv[nt] = z;
    }
    if (kt == jq) {  // diagonal tile: causal mask -> exp gives exact 0
#pragma unroll
      for (int nt = 0; nt < 4; ++nt)
#pragma unroll
        for (int r = 0; r < 4; ++r) {
          const int key = ks + nt * 16 + quad * 4 + r;
          if (key > qrow) sv[nt][r] = -1e30f;
        }
    }
#pragma unroll
    for (int nt = 0; nt < 4; ++nt) {
      const float p0 = __expf(sv[nt][0]);
      const float p1 = __expf(sv[nt][1]);
      const float p2 = __expf(sv[nt][2]);
      const float p3 = __expf(sv[nt][3]);
      lsum += (p0 + p1) + (p2 + p3);
      uint2 pw;
      pw.x = pk2(p0, p1);
      pw.y = pk2(p2, p3);
      ((uint2_a*)&pb[wv][l16][nt * 16 + quad * 4])[0] = pw;
    }
    short8 pf0 = *(const short8_a*)&pb[wv][l16][quad * 8];
    short8 pf1 = *(const short8_a*)&pb[wv][l16][quad * 8 + 32];
#pragma unroll
    for (int nt = 0; nt < 4; ++nt) {
      short8 vf0 = *(const short8_a*)&KV[8 + nt * 2][lane * 8];
      short8 vf1 = *(const short8_a*)&KV[8 + nt * 2 + 1][lane * 8];
      o[nt] = mfma_bf16(vf0, pf0, o[nt]);
      o[nt] = mfma_bf16(vf1, pf1, o[nt]);
    }
    if (it + 1 < nit) {
      __syncthreads();  // all waves done reading KV
      STAGE_KV((kt + 1) * 64);
      __syncthreads();  // staged (vmcnt drained by barrier)
    }
  }
#undef STAGE_KV

  // partial l (sum over 4 quads of this query column) + partial o, raw
  float lr = lsum;
  lr += __shfl_xor(lr, 16);
  lr += __shfl_xor(lr, 32);
  float* op = o_part + ((size_t)s * BT + (size_t)b * TT + qrow) * HH;
#pragma unroll
  for (int nt = 0; nt < 4; ++nt) {
    float4 st;
    st.x = o[nt][0];
    st.y = o[nt][1];
    st.z = o[nt][2];
    st.w = o[nt][3];
    *(float4_a*)(op + nt * 16 + quad * 4) = st;
  }
  if (quad == 0) l_part[(size_t)s * BT + (size_t)b * TT + qrow] = lr;
}

// ---------------------------------------------------------------------------
// Kernel 4: combine. out[bt][h] = sum_s o_part[s][bt][h] / sum_s l_part[s][bt]
// nch = (t>>10)+1 valid slots (uninitialized slots never read). 1024 blocks.
// ---------------------------------------------------------------------------
__global__ __launch_bounds__(256) void comb_kernel(
    const float* __restrict__ o_part, const float* __restrict__ l_part,
    float* __restrict__ out) {
  const int g = (int)blockIdx.x * 256 + (int)threadIdx.x;  // 262144
  const int bt = g >> 3;
  const int h0 = (g & 7) * 8;
  const int tq = bt & (TT - 1);
  const int nch = (tq >> 10) + 1;
  float4 a0 = make_float4(0.f, 0.f, 0.f, 0.f);
  float4 a1 = make_float4(0.f, 0.f, 0.f, 0.f);
  float l = 0.f;
  for (int s = 0; s < nch; ++s) {
    const float* p = o_part + ((size_t)s * BT + bt) * HH + h0;
    float4 x0 = *(const float4_a*)(p);
    float4 x1 = *(const float4_a*)(p + 4);
    a0.x += x0.x; a0.y += x0.y; a0.z += x0.z; a0.w += x0.w;
    a1.x += x1.x; a1.y += x1.y; a1.z += x1.z; a1.w += x1.w;
    l += l_part[(size_t)s * BT + bt];
  }
  const float inv = 1.0f / l;
  a0.x *= inv; a0.y *= inv; a0.z *= inv; a0.w *= inv;
  a1.x *= inv; a1.y *= inv; a1.z *= inv; a1.w *= inv;
  float* op = out + (size_t)bt * HH + h0;
  *(float4_a*)(op) = a0;
  *(float4_a*)(op + 4) = a1;
}

// ---------------------------------------------------------------------------
extern "C" void kernel_launch(void* const* d_in, const int* in_sizes, int n_in,
                              void* d_out, int out_size, void* d_ws, size_t ws_size,
                              hipStream_t stream) {
  const float* x = (const float*)d_in[0];
  const float* Wk = (const float*)d_in[1];
  const float* Wq = (const float*)d_in[2];
  const float* Wv = (const float*)d_in[3];
  float* out = (float*)d_out;

  // ws: k|q|vT (bf16, 4 MiB each) | wt3 (384 KiB) | o_part fp32 [4][B*T][64]
  // (32 MiB) | l_part fp32 [4][B*T] (512 KiB). Total ~44.9 MiB.
  unsigned short* kws = (unsigned short*)d_ws;
  unsigned short* qws = kws + (size_t)BT * HH;
  unsigned short* vtws = qws + (size_t)BT * HH;
  unsigned short* wt3 = vtws + (size_t)BT * HH;
  float* o_part = (float*)((char*)d_ws + 12976128);
  float* l_part = (float*)((char*)d_ws + 46530560);

  hipLaunchKernelGGL(wt_kernel, dim3(16, 3), dim3(256), 0, stream, Wk, Wq, Wv, wt3);
  hipLaunchKernelGGL(proj_kernel, dim3(1024), dim3(256), 0, stream, x, wt3, kws,
                     qws, vtws);
  hipLaunchKernelGGL(attn_kernel, dim3(1280), dim3(256), 0, stream, kws, qws, vtws,
                     o_part, l_part);
  hipLaunchKernelGGL(comb_kernel, dim3(1024), dim3(256), 0, stream, o_part, l_part,
                     out);
}